// Round 1
// baseline (257.642 us; speedup 1.0000x reference)
//
#include <hip/hip_runtime.h>
#include <cstdint>
#include <cstddef>

#define Bn 8192
#define Dn 1024
#define Hn 1024
#define En 8
#define MT 128
#define MAX_TILES (Bn / MT + En)   // 72
#define PERM_N (Bn + En * MT)      // 9216

typedef unsigned short u16;
typedef __bf16 bf16x8 __attribute__((ext_vector_type(8)));
typedef float f32x4 __attribute__((ext_vector_type(4)));

// ---------- helpers ----------
__device__ __forceinline__ u16 f2bf(float f) {
  unsigned int u = __float_as_uint(f);
  unsigned int r = u + 0x7fffu + ((u >> 16) & 1u);   // RNE
  return (u16)(r >> 16);
}

__device__ __forceinline__ void gld16(const void* g, void* l) {
  __builtin_amdgcn_global_load_lds(
      (const __attribute__((address_space(1))) void*)g,
      (__attribute__((address_space(3))) void*)l, 16, 0, 0);
}

// ---------- prep kernels ----------
__global__ void count_k(const int* __restrict__ sidx, int* __restrict__ cnt) {
  int b = blockIdx.x * blockDim.x + threadIdx.x;
  if (b < Bn) atomicAdd(&cnt[sidx[b]], 1);
}

__global__ void plan_k(const int* __restrict__ cnt, int* __restrict__ off,
                       int* __restrict__ ntiles, int* __restrict__ tileE,
                       int* __restrict__ tileR) {
  if (threadIdx.x == 0) {
    int o = 0, t = 0;
    for (int e = 0; e < En; e++) {
      off[e] = o;
      int nt = (cnt[e] + MT - 1) / MT;
      for (int i = 0; i < nt; i++) { tileE[t] = e; tileR[t] = o + i * MT; t++; }
      o += nt * MT;
    }
    off[En] = o;
    *ntiles = t;
  }
}

__global__ void scatter_k(const int* __restrict__ sidx, const int* __restrict__ off,
                          int* __restrict__ cur, int* __restrict__ perm) {
  int b = blockIdx.x * blockDim.x + threadIdx.x;
  if (b < Bn) {
    int e = sidx[b];
    int p = atomicAdd(&cur[e], 1);
    perm[off[e] + p] = b;
  }
}

__global__ void cvt_x_k(const float* __restrict__ x, u16* __restrict__ xb) {
  size_t i = ((size_t)blockIdx.x * blockDim.x + threadIdx.x) * 4;
  float4 v = *(const float4*)(x + i);
  ushort4 o;
  o.x = f2bf(v.x); o.y = f2bf(v.y); o.z = f2bf(v.z); o.w = f2bf(v.w);
  *(ushort4*)(xb + i) = o;
}

// W1 [E][D][H] fp32  ->  W1t [E][H][D] bf16 (32x32 LDS tile transpose)
__global__ void cvt_w1_k(const float* __restrict__ W1, u16* __restrict__ W1t) {
  __shared__ float tile[32][33];
  int e = blockIdx.z;
  int k0 = blockIdx.y * 32;   // D dim
  int n0 = blockIdx.x * 32;   // H dim
  int tx = threadIdx.x & 31, ty = threadIdx.x >> 5;  // ty 0..7
  const float* src = W1 + ((size_t)e << 20) + (size_t)k0 * Hn + n0;
  for (int i = 0; i < 4; i++) {
    int r = ty + i * 8;
    tile[r][tx] = src[(size_t)r * Hn + tx];
  }
  __syncthreads();
  u16* dst = W1t + ((size_t)e << 20) + (size_t)n0 * Dn + k0;
  for (int i = 0; i < 4; i++) {
    int r = ty + i * 8;
    dst[(size_t)r * Dn + tx] = f2bf(tile[tx][r]);
  }
}

// ---------- grouped GEMM + fused layer-2 partial logits ----------
__global__ __launch_bounds__(256) void gemm_k(
    const u16* __restrict__ xb, const u16* __restrict__ w1t,
    const float* __restrict__ b1, const float* __restrict__ w2,
    const int* __restrict__ perm, const int* __restrict__ ntiles,
    const int* __restrict__ tileE, const int* __restrict__ tileR,
    float* __restrict__ out) {
  int tb = blockIdx.x;
  if (tb >= *ntiles) return;
  int e = tileE[tb];
  int row0 = tileR[tb];
  int n0 = blockIdx.y * 128;

  __shared__ u16 As[128 * 32];
  __shared__ u16 Bs[128 * 32];

  int tid = threadIdx.x;
  int lane = tid & 63, w = tid >> 6;
  int wm = w >> 1, wn = w & 1;

  // staging addresses: each wave stages 32 rows of A and 32 rows of B (2 x 16-row instrs)
  int srow = lane >> 2;           // 0..15
  int scol = (lane & 3) * 8;      // bf16-element offset in row (8 elems = 16B)
  const u16* aG[2]; const u16* bG[2];
  u16* aL[2]; u16* bL[2];
  for (int j = 0; j < 2; j++) {
    int rl = 32 * w + 16 * j + srow;
    int tok = perm[row0 + rl];
    if (tok < 0) tok = 0;                  // padded row: load any valid row
    aG[j] = xb + (size_t)tok * Dn + scol;
    aL[j] = As + (32 * w + 16 * j) * 32;
    bG[j] = w1t + ((size_t)e << 20) + (size_t)(n0 + rl) * Dn + scol;
    bL[j] = Bs + (32 * w + 16 * j) * 32;
  }

  f32x4 acc[4][4];
  for (int i = 0; i < 4; i++)
    for (int j = 0; j < 4; j++)
      acc[i][j] = (f32x4){0.f, 0.f, 0.f, 0.f};

  int fr = lane & 15;
  int fk = (lane >> 4) * 8;

  for (int k0 = 0; k0 < Dn; k0 += 32) {
    __syncthreads();
    gld16(aG[0] + k0, aL[0]);
    gld16(aG[1] + k0, aL[1]);
    gld16(bG[0] + k0, bL[0]);
    gld16(bG[1] + k0, bL[1]);
    __syncthreads();
    bf16x8 af[4], bfr[4];
    for (int i = 0; i < 4; i++)
      af[i] = *(const bf16x8*)(As + (wm * 64 + i * 16 + fr) * 32 + fk);
    for (int j = 0; j < 4; j++)
      bfr[j] = *(const bf16x8*)(Bs + (wn * 64 + j * 16 + fr) * 32 + fk);
    for (int i = 0; i < 4; i++)
      for (int j = 0; j < 4; j++)
        acc[i][j] = __builtin_amdgcn_mfma_f32_16x16x32_bf16(af[i], bfr[j], acc[i][j], 0, 0, 0);
  }

  // epilogue: h = relu(acc + b1); partial logits = h . W2[e][col][0..3]; atomic into out
  int fq = lane >> 4;  // 0..3
  float4 w2v[4]; float b1v[4];
  for (int j = 0; j < 4; j++) {
    int col = n0 + wn * 64 + j * 16 + fr;
    w2v[j] = *(const float4*)(w2 + ((size_t)e * Hn + col) * 4);
    b1v[j] = b1[(size_t)e * Hn + col];
  }
  for (int i = 0; i < 4; i++) {
    int rbase = wm * 64 + i * 16 + fq * 4;
    for (int r = 0; r < 4; r++) {
      float s0 = 0.f, s1 = 0.f, s2 = 0.f, s3 = 0.f;
      for (int j = 0; j < 4; j++) {
        float h = acc[i][j][r] + b1v[j];
        h = fmaxf(h, 0.f);
        s0 = fmaf(h, w2v[j].x, s0);
        s1 = fmaf(h, w2v[j].y, s1);
        s2 = fmaf(h, w2v[j].z, s2);
        s3 = fmaf(h, w2v[j].w, s3);
      }
      for (int m = 1; m < 16; m <<= 1) {
        s0 += __shfl_xor(s0, m);
        s1 += __shfl_xor(s1, m);
        s2 += __shfl_xor(s2, m);
        s3 += __shfl_xor(s3, m);
      }
      if (fr == 0) {
        int tok = perm[row0 + rbase + r];
        if (tok >= 0) {
          float* o = out + (size_t)tok * 4;
          atomicAdd(o + 0, s0);
          atomicAdd(o + 1, s1);
          atomicAdd(o + 2, s2);
          atomicAdd(o + 3, s3);
        }
      }
    }
  }
}

// ---------- ordinal probs ----------
__global__ void probs_k(float* __restrict__ out, const float* __restrict__ b2,
                        const int* __restrict__ sidx) {
  int b = blockIdx.x * blockDim.x + threadIdx.x;
  if (b >= Bn) return;
  int e = sidx[b];
  float l0 = out[b * 4 + 0] + b2[e * 4 + 0];
  float l1 = out[b * 4 + 1] + b2[e * 4 + 1];
  float l2 = out[b * 4 + 2] + b2[e * 4 + 2];
  float l3 = out[b * 4 + 3] + b2[e * 4 + 3];
  out[b * 4 + 0] = l0; out[b * 4 + 1] = l1;
  out[b * 4 + 2] = l2; out[b * 4 + 3] = l3;
  float q0 = 1.f / (1.f + expf(-l0));
  float q1 = 1.f / (1.f + expf(-l1));
  float q2 = 1.f / (1.f + expf(-l2));
  float q3 = 1.f / (1.f + expf(-l3));
  const float eps = 1e-8f;
  float p0 = fmaxf(1.f - q0, eps);
  float p1 = fmaxf(q0 - q1, eps);
  float p2 = fmaxf(q1 - q2, eps);
  float p3 = fmaxf(q2 - q3, eps);
  float p4 = fmaxf(q3, eps);
  float s = p0 + p1 + p2 + p3 + p4;
  float inv = 1.f / fmaxf(s, eps);
  float* pr = out + (size_t)Bn * 4 + (size_t)b * 5;
  pr[0] = p0 * inv; pr[1] = p1 * inv; pr[2] = p2 * inv;
  pr[3] = p3 * inv; pr[4] = p4 * inv;
}

// ---------- launch ----------
extern "C" void kernel_launch(void* const* d_in, const int* in_sizes, int n_in,
                              void* d_out, int out_size, void* d_ws, size_t ws_size,
                              hipStream_t stream) {
  const float* x  = (const float*)d_in[0];
  const int* sidx = (const int*)d_in[1];
  const float* W1 = (const float*)d_in[2];
  const float* b1 = (const float*)d_in[3];
  const float* W2 = (const float*)d_in[4];
  const float* b2 = (const float*)d_in[5];
  float* out = (float*)d_out;

  uint8_t* w = (uint8_t*)d_ws;
  int* cnt    = (int*)(w + 0);     // 8 ints
  int* cur    = (int*)(w + 32);    // 8 ints
  int* off    = (int*)(w + 64);    // 9 ints
  int* ntiles = (int*)(w + 128);   // 1 int
  int* tileE  = (int*)(w + 192);   // <=72 ints
  int* tileR  = (int*)(w + 576);   // <=72 ints
  int* perm   = (int*)(w + 1024);  // 9216 ints
  u16* xb     = (u16*)(w + 40960);                      // 16 MiB
  u16* w1t    = (u16*)(w + 40960 + (size_t)16777216);   // 16 MiB

  hipMemsetAsync(w, 0, 64, stream);                          // cnt + cur
  hipMemsetAsync(perm, 0xFF, PERM_N * sizeof(int), stream);  // perm = -1
  hipMemsetAsync(d_out, 0, (size_t)Bn * 4 * sizeof(float), stream);  // logits acc

  count_k<<<Bn / 256, 256, 0, stream>>>(sidx, cnt);
  plan_k<<<1, 64, 0, stream>>>(cnt, off, ntiles, tileE, tileR);
  scatter_k<<<Bn / 256, 256, 0, stream>>>(sidx, off, cur, perm);
  cvt_x_k<<<(Bn * Dn) / (256 * 4), 256, 0, stream>>>(x, xb);
  cvt_w1_k<<<dim3(Hn / 32, Dn / 32, En), 256, 0, stream>>>(W1, w1t);
  gemm_k<<<dim3(MAX_TILES, Hn / 128), 256, 0, stream>>>(xb, w1t, b1, W2, perm,
                                                        ntiles, tileE, tileR, out);
  probs_k<<<Bn / 256, 256, 0, stream>>>(out, b2, sidx);
}

// Round 2
// 180.972 us; speedup vs baseline: 1.4237x; 1.4237x over previous
//
#include <hip/hip_runtime.h>
#include <cstdint>
#include <cstddef>

#define Bn 8192
#define Dn 1024
#define Hn 1024
#define En 8
#define MT 128
#define MAX_TILES (Bn / MT + En)   // 72
#define PERM_N (Bn + En * MT)      // 9216

typedef unsigned short u16;
typedef __bf16 bf16x8 __attribute__((ext_vector_type(8)));
typedef float f32x4 __attribute__((ext_vector_type(4)));
typedef unsigned short ushort8 __attribute__((ext_vector_type(8)));

// ---------- helpers ----------
__device__ __forceinline__ u16 f2bf(float f) {
  unsigned int u = __float_as_uint(f);
  unsigned int r = u + 0x7fffu + ((u >> 16) & 1u);   // RNE
  return (u16)(r >> 16);
}

__device__ __forceinline__ void gld16(const void* g, void* l) {
  __builtin_amdgcn_global_load_lds(
      (const __attribute__((address_space(1))) void*)g,
      (__attribute__((address_space(3))) void*)l, 16, 0, 0);
}

// ---------- routing: count + offsets + scatter in ONE single-block kernel ----------
__global__ __launch_bounds__(1024) void route_k(const int* __restrict__ sidx,
                                                int* __restrict__ off,
                                                int* __restrict__ perm) {
  __shared__ int hist[16][En];   // per-wave histograms
  __shared__ int base[16][En];
  __shared__ int eoff[En + 1];
  int t = threadIdx.x;
  int wv = t >> 6;
  if (t < 16 * En) ((int*)hist)[t] = 0;
  __syncthreads();
  int e8[8], r8[8];
#pragma unroll
  for (int i = 0; i < 8; i++) {
    int e = sidx[t + i * 1024];
    e8[i] = e;
    r8[i] = atomicAdd(&hist[wv][e], 1);   // LDS atomic: rank within wave-stream
  }
  __syncthreads();
  if (t < En) {                  // scan wave histograms per expert
    int s = 0;
    for (int w = 0; w < 16; w++) { base[w][t] = s; s += hist[w][t]; }
    hist[0][t] = s;              // per-expert total
  }
  __syncthreads();
  if (t == 0) {                  // padded exclusive scan -> off[]
    int o = 0;
    for (int e = 0; e < En; e++) {
      eoff[e] = o; off[e] = o;
      o += (hist[0][e] + MT - 1) & ~(MT - 1);
    }
    eoff[En] = o; off[En] = o;
  }
  __syncthreads();
#pragma unroll
  for (int i = 0; i < 8; i++) {
    int e = e8[i];
    perm[eoff[e] + base[wv][e] + r8[i]] = t + i * 1024;
  }
}

// ---------- conversions ----------
__global__ void cvt_x_k(const float* __restrict__ x, u16* __restrict__ xb) {
  size_t i = ((size_t)blockIdx.x * blockDim.x + threadIdx.x) * 8;
  float4 a = *(const float4*)(x + i);
  float4 b = *(const float4*)(x + i + 4);
  ushort8 o;
  o[0] = f2bf(a.x); o[1] = f2bf(a.y); o[2] = f2bf(a.z); o[3] = f2bf(a.w);
  o[4] = f2bf(b.x); o[5] = f2bf(b.y); o[6] = f2bf(b.z); o[7] = f2bf(b.w);
  *(ushort8*)(xb + i) = o;
}

// W1 [E][D][H] fp32  ->  W1t [E][H][D] bf16 (64x64 LDS tile transpose)
__global__ __launch_bounds__(256) void cvt_w1_k(const float* __restrict__ W1,
                                                u16* __restrict__ W1t) {
  __shared__ float tile[64][65];
  int e = blockIdx.z;
  int k0 = blockIdx.y * 64;   // D dim
  int n0 = blockIdx.x * 64;   // H dim
  int c = threadIdx.x & 63, r0 = threadIdx.x >> 6;  // r0 0..3
  const float* src = W1 + ((size_t)e << 20) + (size_t)k0 * Hn + n0;
#pragma unroll
  for (int i = 0; i < 16; i++) {
    int r = r0 + i * 4;
    tile[r][c] = src[(size_t)r * Hn + c];
  }
  __syncthreads();
  u16* dst = W1t + ((size_t)e << 20) + (size_t)n0 * Dn + k0;
#pragma unroll
  for (int i = 0; i < 16; i++) {
    int h = r0 + i * 4;
    dst[(size_t)h * Dn + c] = f2bf(tile[c][h]);   // 64 lanes x 2B = 128B coalesced
  }
}

// ---------- grouped GEMM (double-buffered, swizzled LDS) + fused layer-2 ----------
__global__ __launch_bounds__(256) void gemm_k(
    const u16* __restrict__ xb, const u16* __restrict__ w1t,
    const float* __restrict__ b1, const float* __restrict__ w2,
    const int* __restrict__ perm, const int* __restrict__ off,
    float* __restrict__ out) {
  __shared__ u16 As[2][128 * 32];
  __shared__ u16 Bs[2][128 * 32];

  int tb = blockIdx.x;
  int row0 = tb * MT;
  if (row0 >= off[En]) return;
  int e = 0;
  while (row0 >= off[e + 1]) e++;
  int n0 = blockIdx.y * 128;

  int tid = threadIdx.x;
  int lane = tid & 63, w = tid >> 6;
  int wm = w >> 1, wn = w & 1;

  // staging: lane L -> LDS (row srow, slot L&3); fetch global chunk q = slot ^ swz(row)
  int srow = lane >> 2;
  int slot = lane & 3;
  int q = slot ^ ((srow >> 1) & 3);
  int scol = q * 8;
  const u16* aG[2]; const u16* bG[2];
  u16* aL[2]; u16* bL[2];
#pragma unroll
  for (int j = 0; j < 2; j++) {
    int rl = 32 * w + 16 * j + srow;
    int tok = perm[row0 + rl];
    if (tok < 0) tok = 0;                  // padded row: load any valid row
    aG[j] = xb + (size_t)tok * Dn + scol;
    bG[j] = w1t + ((size_t)e << 20) + (size_t)(n0 + rl) * Dn + scol;
    aL[j] = (u16*)As + (32 * w + 16 * j) * 32;
    bL[j] = (u16*)Bs + (32 * w + 16 * j) * 32;
  }

  f32x4 acc[4][4];
#pragma unroll
  for (int i = 0; i < 4; i++)
#pragma unroll
    for (int j = 0; j < 4; j++)
      acc[i][j] = (f32x4){0.f, 0.f, 0.f, 0.f};

  int fr = lane & 15;
  int qf = lane >> 4;                       // logical 16B chunk (k-block)
  int sw = (fr >> 1) & 3;
  int offA[4], offB[4];
#pragma unroll
  for (int i = 0; i < 4; i++)
    offA[i] = (wm * 64 + i * 16 + fr) * 32 + (qf ^ sw) * 8;
#pragma unroll
  for (int j = 0; j < 4; j++)
    offB[j] = (wn * 64 + j * 16 + fr) * 32 + (qf ^ sw) * 8;

  // prefetch k=0 into buffer 0
  gld16(aG[0], aL[0]); gld16(aG[1], aL[1]);
  gld16(bG[0], bL[0]); gld16(bG[1], bL[1]);

  int cur = 0;
  for (int k0 = 0; k0 < Dn; k0 += 32, cur ^= 1) {
    __syncthreads();   // compiler emits s_waitcnt vmcnt(0) lgkmcnt(0) before barrier
    if (k0 + 32 < Dn) {
      int nb = cur ^ 1;
      gld16(aG[0] + k0 + 32, aL[0] + nb * 4096);
      gld16(aG[1] + k0 + 32, aL[1] + nb * 4096);
      gld16(bG[0] + k0 + 32, bL[0] + nb * 4096);
      gld16(bG[1] + k0 + 32, bL[1] + nb * 4096);
    }
    const u16* Ab = (const u16*)As + cur * 4096;
    const u16* Bb = (const u16*)Bs + cur * 4096;
    bf16x8 af[4], bfr[4];
#pragma unroll
    for (int i = 0; i < 4; i++) af[i] = *(const bf16x8*)(Ab + offA[i]);
#pragma unroll
    for (int j = 0; j < 4; j++) bfr[j] = *(const bf16x8*)(Bb + offB[j]);
#pragma unroll
    for (int i = 0; i < 4; i++)
#pragma unroll
      for (int j = 0; j < 4; j++)
        acc[i][j] = __builtin_amdgcn_mfma_f32_16x16x32_bf16(af[i], bfr[j], acc[i][j], 0, 0, 0);
  }

  // epilogue: h = relu(acc + b1); partial logits = h . W2[e][col][0..3]; atomic into out
  int fq = lane >> 4;
  float4 w2v[4]; float b1v[4];
#pragma unroll
  for (int j = 0; j < 4; j++) {
    int col = n0 + wn * 64 + j * 16 + fr;
    w2v[j] = *(const float4*)(w2 + ((size_t)e * Hn + col) * 4);
    b1v[j] = b1[(size_t)e * Hn + col];
  }
#pragma unroll
  for (int i = 0; i < 4; i++) {
    int rbase = wm * 64 + i * 16 + fq * 4;
#pragma unroll
    for (int r = 0; r < 4; r++) {
      float s0 = 0.f, s1 = 0.f, s2 = 0.f, s3 = 0.f;
#pragma unroll
      for (int j = 0; j < 4; j++) {
        float h = acc[i][j][r] + b1v[j];
        h = fmaxf(h, 0.f);
        s0 = fmaf(h, w2v[j].x, s0);
        s1 = fmaf(h, w2v[j].y, s1);
        s2 = fmaf(h, w2v[j].z, s2);
        s3 = fmaf(h, w2v[j].w, s3);
      }
#pragma unroll
      for (int m = 1; m < 16; m <<= 1) {
        s0 += __shfl_xor(s0, m);
        s1 += __shfl_xor(s1, m);
        s2 += __shfl_xor(s2, m);
        s3 += __shfl_xor(s3, m);
      }
      if (fr == 0) {
        int tok = perm[row0 + rbase + r];
        if (tok >= 0) {
          float* o = out + (size_t)tok * 4;
          atomicAdd(o + 0, s0);
          atomicAdd(o + 1, s1);
          atomicAdd(o + 2, s2);
          atomicAdd(o + 3, s3);
        }
      }
    }
  }
}

// ---------- ordinal probs ----------
__global__ void probs_k(float* __restrict__ out, const float* __restrict__ b2,
                        const int* __restrict__ sidx) {
  int b = blockIdx.x * blockDim.x + threadIdx.x;
  if (b >= Bn) return;
  int e = sidx[b];
  float l0 = out[b * 4 + 0] + b2[e * 4 + 0];
  float l1 = out[b * 4 + 1] + b2[e * 4 + 1];
  float l2 = out[b * 4 + 2] + b2[e * 4 + 2];
  float l3 = out[b * 4 + 3] + b2[e * 4 + 3];
  out[b * 4 + 0] = l0; out[b * 4 + 1] = l1;
  out[b * 4 + 2] = l2; out[b * 4 + 3] = l3;
  float q0 = 1.f / (1.f + expf(-l0));
  float q1 = 1.f / (1.f + expf(-l1));
  float q2 = 1.f / (1.f + expf(-l2));
  float q3 = 1.f / (1.f + expf(-l3));
  const float eps = 1e-8f;
  float p0 = fmaxf(1.f - q0, eps);
  float p1 = fmaxf(q0 - q1, eps);
  float p2 = fmaxf(q1 - q2, eps);
  float p3 = fmaxf(q2 - q3, eps);
  float p4 = fmaxf(q3, eps);
  float s = p0 + p1 + p2 + p3 + p4;
  float inv = 1.f / fmaxf(s, eps);
  float* pr = out + (size_t)Bn * 4 + (size_t)b * 5;
  pr[0] = p0 * inv; pr[1] = p1 * inv; pr[2] = p2 * inv;
  pr[3] = p3 * inv; pr[4] = p4 * inv;
}

// ---------- launch ----------
extern "C" void kernel_launch(void* const* d_in, const int* in_sizes, int n_in,
                              void* d_out, int out_size, void* d_ws, size_t ws_size,
                              hipStream_t stream) {
  const float* x  = (const float*)d_in[0];
  const int* sidx = (const int*)d_in[1];
  const float* W1 = (const float*)d_in[2];
  const float* b1 = (const float*)d_in[3];
  const float* W2 = (const float*)d_in[4];
  const float* b2 = (const float*)d_in[5];
  float* out = (float*)d_out;

  uint8_t* w = (uint8_t*)d_ws;
  int* off  = (int*)(w + 64);     // 9 ints
  int* perm = (int*)(w + 512);    // 9216 ints
  u16* xb   = (u16*)(w + 40960);                      // 16 MiB
  u16* w1t  = (u16*)(w + 40960 + (size_t)16777216);   // 16 MiB

  hipMemsetAsync(perm, 0xFF, PERM_N * sizeof(int), stream);          // perm = -1
  hipMemsetAsync(d_out, 0, (size_t)Bn * 4 * sizeof(float), stream);  // logits acc

  route_k<<<1, 1024, 0, stream>>>(sidx, off, perm);
  cvt_x_k<<<(Bn * Dn) / (256 * 8), 256, 0, stream>>>(x, xb);
  cvt_w1_k<<<dim3(Hn / 64, Dn / 64, En), 256, 0, stream>>>(W1, w1t);
  gemm_k<<<dim3(MAX_TILES, Hn / 128), 256, 0, stream>>>(xb, w1t, b1, W2, perm, off, out);
  probs_k<<<Bn / 256, 256, 0, stream>>>(out, b2, sidx);
}

// Round 3
// 174.673 us; speedup vs baseline: 1.4750x; 1.0361x over previous
//
#include <hip/hip_runtime.h>
#include <cstdint>
#include <cstddef>

#define Bn 8192
#define Dn 1024
#define Hn 1024
#define En 8
#define MT 128
#define NTILE 64
#define NB (Hn / NTILE)            // 16
#define MAX_TILES (Bn / MT + En)   // 72
#define PERM_N (Bn + En * MT)      // 9216

typedef unsigned short u16;
typedef __bf16 bf16x8 __attribute__((ext_vector_type(8)));
typedef float f32x4 __attribute__((ext_vector_type(4)));
typedef unsigned short ushort8 __attribute__((ext_vector_type(8)));

// ---------- helpers ----------
__device__ __forceinline__ u16 f2bf(float f) {
  unsigned int u = __float_as_uint(f);
  unsigned int r = u + 0x7fffu + ((u >> 16) & 1u);   // RNE
  return (u16)(r >> 16);
}

__device__ __forceinline__ void gld16(const void* g, void* l) {
  __builtin_amdgcn_global_load_lds(
      (const __attribute__((address_space(1))) void*)g,
      (__attribute__((address_space(3))) void*)l, 16, 0, 0);
}

// ---------- routing: count + offsets + scatter in ONE single-block kernel ----------
__global__ __launch_bounds__(1024) void route_k(const int* __restrict__ sidx,
                                                int* __restrict__ off,
                                                int* __restrict__ perm) {
  __shared__ int hist[16][En];   // per-wave histograms
  __shared__ int base[16][En];
  __shared__ int eoff[En + 1];
  int t = threadIdx.x;
  int wv = t >> 6;
  if (t < 16 * En) ((int*)hist)[t] = 0;
  __syncthreads();
  int e8[8], r8[8];
#pragma unroll
  for (int i = 0; i < 8; i++) {
    int e = sidx[t + i * 1024];
    e8[i] = e;
    r8[i] = atomicAdd(&hist[wv][e], 1);
  }
  __syncthreads();
  if (t < En) {
    int s = 0;
    for (int w = 0; w < 16; w++) { base[w][t] = s; s += hist[w][t]; }
    hist[0][t] = s;
  }
  __syncthreads();
  if (t == 0) {
    int o = 0;
    for (int e = 0; e < En; e++) {
      eoff[e] = o; off[e] = o;
      o += (hist[0][e] + MT - 1) & ~(MT - 1);
    }
    eoff[En] = o; off[En] = o;
  }
  __syncthreads();
#pragma unroll
  for (int i = 0; i < 8; i++) {
    int e = e8[i];
    perm[eoff[e] + base[wv][e] + r8[i]] = t + i * 1024;
  }
}

// ---------- gather + convert: xbp[p][:] = bf16(x[perm[p]][:]), zeros for pad ----------
__global__ __launch_bounds__(256) void cvt_xp_k(const float* __restrict__ x,
                                                const int* __restrict__ perm,
                                                u16* __restrict__ xbp) {
  size_t idx = ((size_t)blockIdx.x * 256 + threadIdx.x) * 8;
  int p = (int)(idx >> 10);
  int col = (int)(idx & 1023);
  int tok = perm[p];
  ushort8 o;
  if (tok < 0) {
    o = (ushort8){0, 0, 0, 0, 0, 0, 0, 0};
  } else {
    const float* src = x + ((size_t)tok << 10) + col;
    float4 a = *(const float4*)src;
    float4 b = *(const float4*)(src + 4);
    o[0] = f2bf(a.x); o[1] = f2bf(a.y); o[2] = f2bf(a.z); o[3] = f2bf(a.w);
    o[4] = f2bf(b.x); o[5] = f2bf(b.y); o[6] = f2bf(b.z); o[7] = f2bf(b.w);
  }
  *(ushort8*)(xbp + idx) = o;
}

// W1 [E][D][H] fp32 -> W1t [E][H][D] bf16 (64x64 LDS tile transpose, vectorized)
__global__ __launch_bounds__(256) void cvt_w1_k(const float* __restrict__ W1,
                                                u16* __restrict__ W1t) {
  __shared__ float tile[64][65];
  int e = blockIdx.z;
  int k0 = blockIdx.y * 64;   // D dim
  int n0 = blockIdx.x * 64;   // H dim
  int c4 = (threadIdx.x & 15) * 4;
  int r0 = threadIdx.x >> 4;            // 0..15
  const float* src = W1 + ((size_t)e << 20) + (size_t)k0 * Hn + n0;
#pragma unroll
  for (int i = 0; i < 4; i++) {
    int r = r0 + i * 16;
    float4 v = *(const float4*)(src + (size_t)r * Hn + c4);
    tile[r][c4 + 0] = v.x; tile[r][c4 + 1] = v.y;
    tile[r][c4 + 2] = v.z; tile[r][c4 + 3] = v.w;
  }
  __syncthreads();
  u16* dst = W1t + ((size_t)e << 20) + (size_t)n0 * Dn + k0;
#pragma unroll
  for (int i = 0; i < 4; i++) {
    int h = r0 + i * 16;                 // H row
    ushort4 o;
    o.x = f2bf(tile[c4 + 0][h]);
    o.y = f2bf(tile[c4 + 1][h]);
    o.z = f2bf(tile[c4 + 2][h]);
    o.w = f2bf(tile[c4 + 3][h]);
    *(ushort4*)(dst + (size_t)h * Dn + c4) = o;
  }
}

// ---------- grouped GEMM (128x64 tile, dbuf, swizzled LDS) + fused layer-2 ----------
__global__ __launch_bounds__(256) void gemm_k(
    const u16* __restrict__ xbp, const u16* __restrict__ w1t,
    const float* __restrict__ b1, const float* __restrict__ w2,
    const int* __restrict__ off, float* __restrict__ partials) {
  __shared__ u16 As[2][128 * 32];
  __shared__ u16 Bs[2][64 * 32];

  int tb = blockIdx.x;
  int row0 = tb * MT;
  if (row0 >= off[En]) return;
  int e = 0;
  while (row0 >= off[e + 1]) e++;
  int n0 = blockIdx.y * NTILE;

  int tid = threadIdx.x;
  int lane = tid & 63, w = tid >> 6;

  // staging: lane L -> LDS (row srow, slot L&3); fetch global chunk q = slot ^ swz(row)
  int srow = lane >> 2;
  int slot = lane & 3;
  int scol = (slot ^ ((srow >> 1) & 3)) * 8;
  const u16* aG[2]; u16* aL[2];
#pragma unroll
  for (int j = 0; j < 2; j++) {
    int rl = 32 * w + 16 * j + srow;
    aG[j] = xbp + (size_t)(row0 + rl) * Dn + scol;
    aL[j] = (u16*)As + (32 * w + 16 * j) * 32;
  }
  const u16* bG = w1t + ((size_t)e << 20) + (size_t)(n0 + 16 * w + srow) * Dn + scol;
  u16* bL = (u16*)Bs + (16 * w) * 32;

  f32x4 acc[2][4];
#pragma unroll
  for (int i = 0; i < 2; i++)
#pragma unroll
    for (int j = 0; j < 4; j++)
      acc[i][j] = (f32x4){0.f, 0.f, 0.f, 0.f};

  int fr = lane & 15;
  int qf = lane >> 4;
  int qs = (qf ^ ((fr >> 1) & 3)) * 8;
  int offA[2], offB[4];
#pragma unroll
  for (int i = 0; i < 2; i++) offA[i] = (w * 32 + i * 16 + fr) * 32 + qs;
#pragma unroll
  for (int j = 0; j < 4; j++) offB[j] = (j * 16 + fr) * 32 + qs;

  // prefetch k=0 into buffer 0
  gld16(aG[0], aL[0]); gld16(aG[1], aL[1]); gld16(bG, bL);

  int cur = 0;
  for (int k0 = 0; k0 < Dn; k0 += 32, cur ^= 1) {
    __syncthreads();
    if (k0 + 32 < Dn) {
      int nb = cur ^ 1;
      gld16(aG[0] + k0 + 32, aL[0] + nb * 4096);
      gld16(aG[1] + k0 + 32, aL[1] + nb * 4096);
      gld16(bG + k0 + 32, bL + nb * 2048);
    }
    const u16* Ab = (const u16*)As + cur * 4096;
    const u16* Bb = (const u16*)Bs + cur * 2048;
    bf16x8 af[2], bfr[4];
#pragma unroll
    for (int i = 0; i < 2; i++) af[i] = *(const bf16x8*)(Ab + offA[i]);
#pragma unroll
    for (int j = 0; j < 4; j++) bfr[j] = *(const bf16x8*)(Bb + offB[j]);
#pragma unroll
    for (int i = 0; i < 2; i++)
#pragma unroll
      for (int j = 0; j < 4; j++)
        acc[i][j] = __builtin_amdgcn_mfma_f32_16x16x32_bf16(af[i], bfr[j], acc[i][j], 0, 0, 0);
  }

  // epilogue: h = relu(acc + b1); partial = h . W2[e][col][0..3]; one float4 per row
  float4 w2v[4]; float b1v[4];
#pragma unroll
  for (int j = 0; j < 4; j++) {
    int col = n0 + j * 16 + fr;
    w2v[j] = *(const float4*)(w2 + ((size_t)e * Hn + col) * 4);
    b1v[j] = b1[(size_t)e * Hn + col];
  }
#pragma unroll
  for (int i = 0; i < 2; i++) {
#pragma unroll
    for (int r = 0; r < 4; r++) {
      float s0 = 0.f, s1 = 0.f, s2 = 0.f, s3 = 0.f;
#pragma unroll
      for (int j = 0; j < 4; j++) {
        float h = acc[i][j][r] + b1v[j];
        h = fmaxf(h, 0.f);
        s0 = fmaf(h, w2v[j].x, s0);
        s1 = fmaf(h, w2v[j].y, s1);
        s2 = fmaf(h, w2v[j].z, s2);
        s3 = fmaf(h, w2v[j].w, s3);
      }
#pragma unroll
      for (int m = 1; m < 16; m <<= 1) {
        s0 += __shfl_xor(s0, m);
        s1 += __shfl_xor(s1, m);
        s2 += __shfl_xor(s2, m);
        s3 += __shfl_xor(s3, m);
      }
      if (fr == 0) {
        int row = w * 32 + i * 16 + qf * 4 + r;
        *(float4*)(partials + ((size_t)(row0 + row) * NB + blockIdx.y) * 4) =
            make_float4(s0, s1, s2, s3);
      }
    }
  }
}

// ---------- reduce partials + ordinal probs ----------
__global__ void probs_k(const float* __restrict__ partials,
                        const int* __restrict__ perm, const int* __restrict__ off,
                        const int* __restrict__ sidx, const float* __restrict__ b2,
                        float* __restrict__ out) {
  int p = blockIdx.x * blockDim.x + threadIdx.x;
  if (p >= off[En]) return;
  int tok = perm[p];
  if (tok < 0) return;
  int e = sidx[tok];
  float s0 = 0.f, s1 = 0.f, s2 = 0.f, s3 = 0.f;
#pragma unroll
  for (int nb = 0; nb < NB; nb++) {
    float4 v = *(const float4*)(partials + ((size_t)p * NB + nb) * 4);
    s0 += v.x; s1 += v.y; s2 += v.z; s3 += v.w;
  }
  float l0 = s0 + b2[e * 4 + 0];
  float l1 = s1 + b2[e * 4 + 1];
  float l2 = s2 + b2[e * 4 + 2];
  float l3 = s3 + b2[e * 4 + 3];
  out[tok * 4 + 0] = l0; out[tok * 4 + 1] = l1;
  out[tok * 4 + 2] = l2; out[tok * 4 + 3] = l3;
  float q0 = 1.f / (1.f + expf(-l0));
  float q1 = 1.f / (1.f + expf(-l1));
  float q2 = 1.f / (1.f + expf(-l2));
  float q3 = 1.f / (1.f + expf(-l3));
  const float eps = 1e-8f;
  float p0 = fmaxf(1.f - q0, eps);
  float p1 = fmaxf(q0 - q1, eps);
  float p2 = fmaxf(q1 - q2, eps);
  float p3 = fmaxf(q2 - q3, eps);
  float p4 = fmaxf(q3, eps);
  float s = p0 + p1 + p2 + p3 + p4;
  float inv = 1.f / fmaxf(s, eps);
  float* pr = out + (size_t)Bn * 4 + (size_t)tok * 5;
  pr[0] = p0 * inv; pr[1] = p1 * inv; pr[2] = p2 * inv;
  pr[3] = p3 * inv; pr[4] = p4 * inv;
}

// ---------- launch ----------
extern "C" void kernel_launch(void* const* d_in, const int* in_sizes, int n_in,
                              void* d_out, int out_size, void* d_ws, size_t ws_size,
                              hipStream_t stream) {
  const float* x  = (const float*)d_in[0];
  const int* sidx = (const int*)d_in[1];
  const float* W1 = (const float*)d_in[2];
  const float* b1 = (const float*)d_in[3];
  const float* W2 = (const float*)d_in[4];
  const float* b2 = (const float*)d_in[5];
  float* out = (float*)d_out;

  uint8_t* w = (uint8_t*)d_ws;
  int* off  = (int*)(w + 64);     // 9 ints
  int* perm = (int*)(w + 512);    // 9216 ints, ends @ 37376
  u16* xbp      = (u16*)(w + 40960);                     // 18,874,368 B
  u16* w1t      = (u16*)(w + 18919424);                  // 16,777,216 B
  float* parts  = (float*)(w + 35700736);                // 2,359,296 B (~38.1 MB total)

  hipMemsetAsync(perm, 0xFF, PERM_N * sizeof(int), stream);  // perm = -1

  route_k<<<1, 1024, 0, stream>>>(sidx, off, perm);
  cvt_xp_k<<<(PERM_N * Dn) / (256 * 8), 256, 0, stream>>>(x, perm, xbp);
  cvt_w1_k<<<dim3(Hn / 64, Dn / 64, En), 256, 0, stream>>>(W1, w1t);
  gemm_k<<<dim3(MAX_TILES, NB), 256, 0, stream>>>(xbp, w1t, b1, W2, off, parts);
  probs_k<<<(PERM_N + 255) / 256, 256, 0, stream>>>(parts, perm, off, sidx, b2, out);
}

// Round 4
// 160.609 us; speedup vs baseline: 1.6042x; 1.0876x over previous
//
#include <hip/hip_runtime.h>
#include <cstdint>
#include <cstddef>

#define Bn 8192
#define Dn 1024
#define Hn 1024
#define En 8
#define MT 128
#define NB 16                      // 64-col partial chunks per row
#define MTILES (Bn / MT + En)      // 72
#define PERM_N (Bn + En * MT)      // 9216 = 1024*9

typedef unsigned short u16;
typedef __bf16 bf16x8 __attribute__((ext_vector_type(8)));
typedef float f32x4 __attribute__((ext_vector_type(4)));
typedef unsigned short ushort8 __attribute__((ext_vector_type(8)));

// ---------- helpers ----------
__device__ __forceinline__ u16 f2bf(float f) {
  unsigned int u = __float_as_uint(f);
  unsigned int r = u + 0x7fffu + ((u >> 16) & 1u);   // RNE
  return (u16)(r >> 16);
}

__device__ __forceinline__ void gld16(const void* g, void* l) {
  __builtin_amdgcn_global_load_lds(
      (const __attribute__((address_space(1))) void*)g,
      (__attribute__((address_space(3))) void*)l, 16, 0, 0);
}

// wait for own vmcnt<=N (other counters untouched), then workgroup barrier.
// imm: vmcnt[3:0]|expcnt[6:4]|lgkmcnt[11:8]|vmcnt_hi[15:14]
#define PIPE_BARRIER_VM4() do {                    \
    asm volatile("" ::: "memory");                 \
    __builtin_amdgcn_s_waitcnt(0x0F74);            \
    __builtin_amdgcn_s_barrier();                  \
    asm volatile("" ::: "memory");                 \
  } while (0)
#define PIPE_BARRIER_VM0() do {                    \
    asm volatile("" ::: "memory");                 \
    __builtin_amdgcn_s_waitcnt(0x0F70);            \
    __builtin_amdgcn_s_barrier();                  \
    asm volatile("" ::: "memory");                 \
  } while (0)

// ---------- routing: count + offsets + pad-fill + scatter, ONE block ----------
__global__ __launch_bounds__(1024) void route_k(const int* __restrict__ sidx,
                                                int* __restrict__ off,
                                                int* __restrict__ perm) {
  __shared__ int hist[16][En];
  __shared__ int base[16][En];
  __shared__ int eoff[En + 1];
  int t = threadIdx.x;
  int wv = t >> 6;
  if (t < 16 * En) ((int*)hist)[t] = 0;
#pragma unroll
  for (int i = 0; i < PERM_N / 1024; i++) perm[t + i * 1024] = -1;  // pad fill
  __syncthreads();
  int e8[8], r8[8];
#pragma unroll
  for (int i = 0; i < 8; i++) {
    int e = sidx[t + i * 1024];
    e8[i] = e;
    r8[i] = atomicAdd(&hist[wv][e], 1);
  }
  __syncthreads();
  if (t < En) {
    int s = 0;
    for (int w = 0; w < 16; w++) { base[w][t] = s; s += hist[w][t]; }
    hist[0][t] = s;
  }
  __syncthreads();
  if (t == 0) {
    int o = 0;
    for (int e = 0; e < En; e++) {
      eoff[e] = o; off[e] = o;
      o += (hist[0][e] + MT - 1) & ~(MT - 1);
    }
    eoff[En] = o; off[En] = o;
  }
  __syncthreads();
#pragma unroll
  for (int i = 0; i < 8; i++) {
    int e = e8[i];
    perm[eoff[e] + base[wv][e] + r8[i]] = t + i * 1024;
  }
}

// ---------- gather + convert: xbp[p][:] = bf16(x[perm[p]][:]), zeros for pad ----------
__global__ __launch_bounds__(256) void cvt_xp_k(const float* __restrict__ x,
                                                const int* __restrict__ perm,
                                                u16* __restrict__ xbp) {
  size_t idx = ((size_t)blockIdx.x * 256 + threadIdx.x) * 8;
  int p = (int)(idx >> 10);
  int col = (int)(idx & 1023);
  int tok = perm[p];
  ushort8 o;
  if (tok < 0) {
    o = (ushort8){0, 0, 0, 0, 0, 0, 0, 0};
  } else {
    const float* src = x + ((size_t)tok << 10) + col;
    float4 a = *(const float4*)src;
    float4 b = *(const float4*)(src + 4);
    o[0] = f2bf(a.x); o[1] = f2bf(a.y); o[2] = f2bf(a.z); o[3] = f2bf(a.w);
    o[4] = f2bf(b.x); o[5] = f2bf(b.y); o[6] = f2bf(b.z); o[7] = f2bf(b.w);
  }
  *(ushort8*)(xbp + idx) = o;
}

// W1 [E][D][H] fp32 -> W1t [E][H][D] bf16 (64x64 LDS tile transpose, vectorized)
__global__ __launch_bounds__(256) void cvt_w1_k(const float* __restrict__ W1,
                                                u16* __restrict__ W1t) {
  __shared__ float tile[64][65];
  int e = blockIdx.z;
  int k0 = blockIdx.y * 64;   // D dim
  int n0 = blockIdx.x * 64;   // H dim
  int c4 = (threadIdx.x & 15) * 4;
  int r0 = threadIdx.x >> 4;            // 0..15
  const float* src = W1 + ((size_t)e << 20) + (size_t)k0 * Hn + n0;
#pragma unroll
  for (int i = 0; i < 4; i++) {
    int r = r0 + i * 16;
    float4 v = *(const float4*)(src + (size_t)r * Hn + c4);
    tile[r][c4 + 0] = v.x; tile[r][c4 + 1] = v.y;
    tile[r][c4 + 2] = v.z; tile[r][c4 + 3] = v.w;
  }
  __syncthreads();
  u16* dst = W1t + ((size_t)e << 20) + (size_t)n0 * Dn + k0;
#pragma unroll
  for (int i = 0; i < 4; i++) {
    int h = r0 + i * 16;
    ushort4 o;
    o.x = f2bf(tile[c4 + 0][h]);
    o.y = f2bf(tile[c4 + 1][h]);
    o.z = f2bf(tile[c4 + 2][h]);
    o.w = f2bf(tile[c4 + 3][h]);
    *(ushort4*)(dst + (size_t)h * Dn + c4) = o;
  }
}

// ---------- grouped GEMM: 128x128 tile, 3-stage pipeline, fine-grained vmcnt ----------
__global__ __launch_bounds__(256) void gemm_k(
    const u16* __restrict__ xbp, const u16* __restrict__ w1t,
    const float* __restrict__ b1, const float* __restrict__ w2,
    const int* __restrict__ off, float* __restrict__ partials) {
  __shared__ u16 As[3][4096];   // 3 stages x 128 rows x 32 k (8 KB)
  __shared__ u16 Bs[3][4096];

  int n0 = blockIdx.x * 128;            // x = n-tile: maps 1:1 onto XCDs
  int row0 = blockIdx.y * MT;
  if (row0 >= off[En]) return;
  int e = 0;
  while (row0 >= off[e + 1]) e++;

  int tid = threadIdx.x;
  int lane = tid & 63, w = tid >> 6;
  int wm = w >> 1, wn = w & 1;

  // staging: HW puts lane L at LDS base + L*16B -> (row L>>2, slot L&3).
  // source chunk q = slot ^ swz(row) implements the xor swizzle.
  int srow = lane >> 2;
  int slot = lane & 3;
  int scol = (slot ^ ((srow >> 1) & 3)) * 8;
  const u16* aG[2]; const u16* bG[2];
  int lOff[2];
#pragma unroll
  for (int j = 0; j < 2; j++) {
    int rl = 32 * w + 16 * j + srow;
    aG[j] = xbp + (size_t)(row0 + rl) * Dn + scol;
    bG[j] = w1t + ((size_t)e << 20) + (size_t)(n0 + rl) * Dn + scol;
    lOff[j] = (32 * w + 16 * j) * 32;   // wave-uniform LDS base (elements)
  }

  f32x4 acc[4][4];
#pragma unroll
  for (int i = 0; i < 4; i++)
#pragma unroll
    for (int j = 0; j < 4; j++)
      acc[i][j] = (f32x4){0.f, 0.f, 0.f, 0.f};

  int fr = lane & 15;
  int qf = lane >> 4;
  int qs = (qf ^ ((fr >> 1) & 3)) * 8;
  int offA[4], offB[4];
#pragma unroll
  for (int i = 0; i < 4; i++)
    offA[i] = (wm * 64 + i * 16 + fr) * 32 + qs;
#pragma unroll
  for (int j = 0; j < 4; j++)
    offB[j] = (wn * 64 + j * 16 + fr) * 32 + qs;

  // prologue: stages 0,1 in flight (8 loads/thread)
#pragma unroll
  for (int it = 0; it < 2; it++) {
    int ko = it * 32;
    gld16(aG[0] + ko, (u16*)As[it] + lOff[0]);
    gld16(aG[1] + ko, (u16*)As[it] + lOff[1]);
    gld16(bG[0] + ko, (u16*)Bs[it] + lOff[0]);
    gld16(bG[1] + ko, (u16*)Bs[it] + lOff[1]);
  }

#pragma unroll
  for (int i = 0; i < 31; i++) {
    PIPE_BARRIER_VM4();                 // stage-i loads done; stage-(i+1) in flight
    if (i + 2 < 32) {
      int s = (i + 2) % 3;
      int ko = (i + 2) * 32;
      gld16(aG[0] + ko, (u16*)As[s] + lOff[0]);
      gld16(aG[1] + ko, (u16*)As[s] + lOff[1]);
      gld16(bG[0] + ko, (u16*)Bs[s] + lOff[0]);
      gld16(bG[1] + ko, (u16*)Bs[s] + lOff[1]);
    }
    const u16* Ab = (const u16*)As[i % 3];
    const u16* Bb = (const u16*)Bs[i % 3];
    bf16x8 af[4], bfr[4];
#pragma unroll
    for (int ii = 0; ii < 4; ii++) af[ii] = *(const bf16x8*)(Ab + offA[ii]);
#pragma unroll
    for (int jj = 0; jj < 4; jj++) bfr[jj] = *(const bf16x8*)(Bb + offB[jj]);
#pragma unroll
    for (int ii = 0; ii < 4; ii++)
#pragma unroll
      for (int jj = 0; jj < 4; jj++)
        acc[ii][jj] = __builtin_amdgcn_mfma_f32_16x16x32_bf16(af[ii], bfr[jj], acc[ii][jj], 0, 0, 0);
  }
  {                                     // peeled last iteration (full drain)
    PIPE_BARRIER_VM0();
    const u16* Ab = (const u16*)As[31 % 3];
    const u16* Bb = (const u16*)Bs[31 % 3];
    bf16x8 af[4], bfr[4];
#pragma unroll
    for (int ii = 0; ii < 4; ii++) af[ii] = *(const bf16x8*)(Ab + offA[ii]);
#pragma unroll
    for (int jj = 0; jj < 4; jj++) bfr[jj] = *(const bf16x8*)(Bb + offB[jj]);
#pragma unroll
    for (int ii = 0; ii < 4; ii++)
#pragma unroll
      for (int jj = 0; jj < 4; jj++)
        acc[ii][jj] = __builtin_amdgcn_mfma_f32_16x16x32_bf16(af[ii], bfr[jj], acc[ii][jj], 0, 0, 0);
  }

  // epilogue: h = relu(acc + b1); partial = h . W2[e][col][0..3]; float4 per row/chunk
  int fq = lane >> 4;
  float4 w2v[4]; float b1v[4];
#pragma unroll
  for (int j = 0; j < 4; j++) {
    int col = n0 + wn * 64 + j * 16 + fr;
    w2v[j] = *(const float4*)(w2 + ((size_t)e * Hn + col) * 4);
    b1v[j] = b1[(size_t)e * Hn + col];
  }
  int chunk = blockIdx.x * 2 + wn;      // 64-col chunk 0..15
#pragma unroll
  for (int i = 0; i < 4; i++) {
    int rbase = wm * 64 + i * 16 + fq * 4;
#pragma unroll
    for (int r = 0; r < 4; r++) {
      float s0 = 0.f, s1 = 0.f, s2 = 0.f, s3 = 0.f;
#pragma unroll
      for (int j = 0; j < 4; j++) {
        float h = acc[i][j][r] + b1v[j];
        h = fmaxf(h, 0.f);
        s0 = fmaf(h, w2v[j].x, s0);
        s1 = fmaf(h, w2v[j].y, s1);
        s2 = fmaf(h, w2v[j].z, s2);
        s3 = fmaf(h, w2v[j].w, s3);
      }
#pragma unroll
      for (int m = 1; m < 16; m <<= 1) {
        s0 += __shfl_xor(s0, m);
        s1 += __shfl_xor(s1, m);
        s2 += __shfl_xor(s2, m);
        s3 += __shfl_xor(s3, m);
      }
      if (fr == 0) {
        int row = row0 + rbase + r;
        *(float4*)(partials + ((size_t)row * NB + chunk) * 4) =
            make_float4(s0, s1, s2, s3);
      }
    }
  }
}

// ---------- reduce partials + ordinal probs ----------
__global__ void probs_k(const float* __restrict__ partials,
                        const int* __restrict__ perm, const int* __restrict__ off,
                        const int* __restrict__ sidx, const float* __restrict__ b2,
                        float* __restrict__ out) {
  int p = blockIdx.x * blockDim.x + threadIdx.x;
  if (p >= off[En]) return;
  int tok = perm[p];
  if (tok < 0) return;
  int e = sidx[tok];
  float s0 = 0.f, s1 = 0.f, s2 = 0.f, s3 = 0.f;
#pragma unroll
  for (int nb = 0; nb < NB; nb++) {
    float4 v = *(const float4*)(partials + ((size_t)p * NB + nb) * 4);
    s0 += v.x; s1 += v.y; s2 += v.z; s3 += v.w;
  }
  float l0 = s0 + b2[e * 4 + 0];
  float l1 = s1 + b2[e * 4 + 1];
  float l2 = s2 + b2[e * 4 + 2];
  float l3 = s3 + b2[e * 4 + 3];
  out[tok * 4 + 0] = l0; out[tok * 4 + 1] = l1;
  out[tok * 4 + 2] = l2; out[tok * 4 + 3] = l3;
  float q0 = 1.f / (1.f + expf(-l0));
  float q1 = 1.f / (1.f + expf(-l1));
  float q2 = 1.f / (1.f + expf(-l2));
  float q3 = 1.f / (1.f + expf(-l3));
  const float eps = 1e-8f;
  float p0 = fmaxf(1.f - q0, eps);
  float p1 = fmaxf(q0 - q1, eps);
  float p2 = fmaxf(q1 - q2, eps);
  float p3 = fmaxf(q2 - q3, eps);
  float p4 = fmaxf(q3, eps);
  float s = p0 + p1 + p2 + p3 + p4;
  float inv = 1.f / fmaxf(s, eps);
  float* pr = out + (size_t)Bn * 4 + (size_t)tok * 5;
  pr[0] = p0 * inv; pr[1] = p1 * inv; pr[2] = p2 * inv;
  pr[3] = p3 * inv; pr[4] = p4 * inv;
}

// ---------- launch ----------
extern "C" void kernel_launch(void* const* d_in, const int* in_sizes, int n_in,
                              void* d_out, int out_size, void* d_ws, size_t ws_size,
                              hipStream_t stream) {
  const float* x  = (const float*)d_in[0];
  const int* sidx = (const int*)d_in[1];
  const float* W1 = (const float*)d_in[2];
  const float* b1 = (const float*)d_in[3];
  const float* W2 = (const float*)d_in[4];
  const float* b2 = (const float*)d_in[5];
  float* out = (float*)d_out;

  uint8_t* w = (uint8_t*)d_ws;
  int* off  = (int*)(w + 64);     // 9 ints
  int* perm = (int*)(w + 512);    // 9216 ints
  u16* xbp      = (u16*)(w + 40960);                     // 18,874,368 B
  u16* w1t      = (u16*)(w + 18919424);                  // 16,777,216 B
  float* parts  = (float*)(w + 35700736);                // 2,359,296 B

  route_k<<<1, 1024, 0, stream>>>(sidx, off, perm);
  cvt_xp_k<<<(PERM_N * Dn) / (256 * 8), 256, 0, stream>>>(x, perm, xbp);
  cvt_w1_k<<<dim3(Hn / 64, Dn / 64, En), 256, 0, stream>>>(W1, w1t);
  gemm_k<<<dim3(Hn / 128, MTILES), 256, 0, stream>>>(xbp, w1t, b1, W2, off, parts);
  probs_k<<<(PERM_N + 255) / 256, 256, 0, stream>>>(parts, perm, off, sidx, b2, out);
}